// Round 5
// baseline (1509.826 us; speedup 1.0000x reference)
//
#include <hip/hip_runtime.h>

typedef __attribute__((ext_vector_type(8))) short bf16x8;
typedef __attribute__((ext_vector_type(4))) float f32x4;

#define FP const float* __restrict__

__device__ __forceinline__ short f2bf(float f) {
    unsigned u = __float_as_uint(f);
    u += 0x7fffu + ((u >> 16) & 1u);
    return (short)(u >> 16);
}
__device__ __forceinline__ float bf2f(short s) {
    return __uint_as_float(((unsigned)(unsigned short)s) << 16);
}
__device__ __forceinline__ float v_exp2(float x) { float r; asm("v_exp_f32 %0, %1" : "=v"(r) : "v"(x)); return r; }
__device__ __forceinline__ float v_log2(float x) { float r; asm("v_log_f32 %0, %1" : "=v"(r) : "v"(x)); return r; }

__device__ __forceinline__ float fexp(float x) {       // e^x
    return v_exp2(1.44269504f * x);
}
__device__ __forceinline__ float sp(float x) {         // softplus, branch-free
    return fmaxf(x, 0.f) + 0.69314718f * v_log2(1.f + v_exp2(-1.44269504f * fabsf(x)));
}
__device__ __forceinline__ float silu_f(float x) {
    return x * __builtin_amdgcn_rcpf(1.f + v_exp2(-1.44269504f * x));
}

// A-operand = W^T tile: lane l holds W[k, c0+(l&15)], k = 8*(l>>4)+j. W is [32+,ld] f32.
__device__ __forceinline__ bf16x8 load_wfrag(FP w, int ld, int c0, int l) {
    const int c = c0 + (l & 15);
    const int k0 = 8 * (l >> 4);
    bf16x8 f;
#pragma unroll
    for (int j = 0; j < 8; ++j) f[j] = f2bf(w[(k0 + j) * ld + c]);
    return f;
}
// B-operand = x^T tile: lane l holds x[r0+(l&15), 8*(l>>4)+j]; x is [R,32] f32 row-major.
__device__ __forceinline__ bf16x8 load_xfrag32(FP x, int r0, int l, int R) {
    int row = r0 + (l & 15);
    row = row < R ? row : R - 1;
    const float* p = x + (size_t)row * 32 + 8 * (l >> 4);
    const float4 a = *(const float4*)p;
    const float4 b = *(const float4*)(p + 4);
    bf16x8 f;
    f[0]=f2bf(a.x); f[1]=f2bf(a.y); f[2]=f2bf(a.z); f[3]=f2bf(a.w);
    f[4]=f2bf(b.x); f[5]=f2bf(b.y); f[6]=f2bf(b.z); f[7]=f2bf(b.w);
    return f;
}

// ---------------------------------------------------------------------------
// kA: A = bf16(atom @ Wa) [N,128], PERMUTED per row: short idx 32q+4mb+r
//     (feature f = 16*mb + 4*q + r)
// ---------------------------------------------------------------------------
__global__ __launch_bounds__(256) void kA(FP x, FP W0, short* __restrict__ Aout, int R)
{
    const int l = threadIdx.x & 63;
    const int wv = blockIdx.x * 4 + (threadIdx.x >> 6);
    const int nw = gridDim.x * 4;
    bf16x8 wf[8];
#pragma unroll
    for (int mb = 0; mb < 8; ++mb) wf[mb] = load_wfrag(W0, 128, 16 * mb, l);
    const f32x4 z = {0.f, 0.f, 0.f, 0.f};
    const int nt = (R + 15) >> 4;
    for (int t = wv; t < nt; t += nw) {
        bf16x8 xf = load_xfrag32(x, t * 16, l, R);
        const int node = t * 16 + (l & 15);
        const int q = l >> 4;
#pragma unroll
        for (int mb = 0; mb < 8; ++mb) {
            f32x4 c = __builtin_amdgcn_mfma_f32_16x16x32_bf16(wf[mb], xf, z, 0, 0, 0);
            short4 s = { f2bf(c[0]), f2bf(c[1]), f2bf(c[2]), f2bf(c[3]) };
            if (node < R) *(short4*)&Aout[(size_t)node * 128 + 32 * q + 4 * mb] = s;
        }
    }
}

// ---------------------------------------------------------------------------
// kPQ: PQ = bf16(out @ [W1a | W1b])  [N,256], natural feature order
// ---------------------------------------------------------------------------
__global__ __launch_bounds__(256) void kPQ(FP x, FP W1g, short* __restrict__ PQ, int R)
{
    const int l = threadIdx.x & 63;
    const int wv = blockIdx.x * 4 + (threadIdx.x >> 6);
    const int nw = gridDim.x * 4;
    bf16x8 wf[16];
#pragma unroll
    for (int mb = 0; mb < 8; ++mb) wf[mb] = load_wfrag(W1g, 128, 16 * mb, l);
#pragma unroll
    for (int mb = 0; mb < 8; ++mb) wf[8 + mb] = load_wfrag(W1g + 32 * 128, 128, 16 * mb, l);
    const f32x4 z = {0.f, 0.f, 0.f, 0.f};
    const int nt = (R + 15) >> 4;
    for (int t = wv; t < nt; t += nw) {
        bf16x8 xf = load_xfrag32(x, t * 16, l, R);
        const int node = t * 16 + (l & 15);
        const int fb = 4 * (l >> 4);
#pragma unroll
        for (int mb = 0; mb < 16; ++mb) {
            f32x4 c = __builtin_amdgcn_mfma_f32_16x16x32_bf16(wf[mb], xf, z, 0, 0, 0);
            short4 s = { f2bf(c[0]), f2bf(c[1]), f2bf(c[2]), f2bf(c[3]) };
            if (node < R) *(short4*)&PQ[(size_t)node * 256 + 16 * mb + fb] = s;
        }
    }
}

// ---------------------------------------------------------------------------
// kB: Ee = ef@We via MFMA; hi/hj = sp(A[i/j]+Ee); att dot -> alpha0 + BN stats
// A-rows gathered 16-lanes-per-row (4 rows/instr, full-line requests) -> LDS,
// consumed as ds_read_b128 in the MFMA-pinned lane layout.
// ---------------------------------------------------------------------------
__global__ __launch_bounds__(256) void kB(
    FP ef, const int* __restrict__ eidx, const short* __restrict__ Abf,
    FP We, FP attg, float* __restrict__ alpha, float* __restrict__ bnstat, int E)
{
    __shared__ float attl[256];
    __shared__ __align__(16) short As[4][32 * 136];   // 34.8 KB: 32 rows x 272B stride
    const int t = threadIdx.x;
    if (t < 64) ((float4*)attl)[t] = ((const float4*)attg)[t];
    __syncthreads();

    const int l = t & 63, q = l >> 4, e15 = l & 15, wvb = t >> 6;
    const int gr = l >> 4, gc = l & 15;               // gather: row-sub, chunk
    short* Asw = As[wvb];
    const int wv = blockIdx.x * 4 + wvb, nw = gridDim.x * 4;
    bf16x8 wf[8];
#pragma unroll
    for (int mb = 0; mb < 8; ++mb) wf[mb] = load_wfrag(We, 128, 16 * mb, l);
    const f32x4 z = {0.f, 0.f, 0.f, 0.f};
    float bs[4] = {0,0,0,0}, bq2[4] = {0,0,0,0};

    const int nt = E >> 4;
    for (int tt = wv; tt < nt; tt += nw) {
        const int tb = tt * 16;
        // gather 32 rows (0..15 = A[i], 16..31 = A[j]); 16 lanes cover one 256B row
#pragma unroll
        for (int g = 0; g < 8; ++g) {
            const int rsel = g * 4 + gr;
            const int node = eidx[tb + (rsel & 15) + ((rsel >> 4) ? E : 0)];
            const float4 v = *(const float4*)&Abf[(size_t)node * 128 + gc * 8];
            *(float4*)&Asw[rsel * 136 + gc * 8] = v;
        }
        bf16x8 xf = load_xfrag32(ef, tb, l, E);
        f32x4 acc[8];
#pragma unroll
        for (int mb = 0; mb < 8; ++mb)
            acc[mb] = __builtin_amdgcn_mfma_f32_16x16x32_bf16(wf[mb], xf, z, 0, 0, 0);

        const int e = tb + e15;
        float ph[4] = {0,0,0,0};
#pragma unroll
        for (int p = 0; p < 4; ++p) {
            const bf16x8 Ai = *(const bf16x8*)&Asw[e15 * 136 + 32 * q + 8 * p];
            const bf16x8 Aj = *(const bf16x8*)&Asw[(16 + e15) * 136 + 32 * q + 8 * p];
#pragma unroll
            for (int jj = 0; jj < 8; ++jj) {
                const float ev = acc[2 * p + (jj >> 2)][jj & 3];
                const int c = (jj >> 2) * 16 + 4 * q + (jj & 3);
                ph[p] += sp(bf2f(Ai[jj]) + ev) * attl[p * 64 + c]
                       + sp(bf2f(Aj[jj]) + ev) * attl[p * 64 + 32 + c];
            }
        }
        float4 a0v;
#pragma unroll
        for (int h = 0; h < 4; ++h) {
            float v = ph[h];
            v += __shfl_xor(v, 16);
            v += __shfl_xor(v, 32);
            (&a0v.x)[h] = sp(v);
        }
        if (q == 0) {
            *(float4*)&alpha[(size_t)e * 4] = a0v;
#pragma unroll
            for (int h = 0; h < 4; ++h) {
                const float a0 = (&a0v.x)[h];
                bs[h] += a0; bq2[h] += a0 * a0;
            }
        }
    }
#pragma unroll
    for (int h = 0; h < 4; ++h) {
        float v = bs[h], w = bq2[h];
#pragma unroll
        for (int d = 1; d < 64; d <<= 1) { v += __shfl_xor(v, d); w += __shfl_xor(w, d); }
        if (l == 0) { atomicAdd(&bnstat[h], v); atomicAdd(&bnstat[4 + h], w); }
    }
}

// k2: finalize BN scale/shift
__global__ void k2_bn(const float* __restrict__ bnstat, FP gam, FP bet,
                      float* __restrict__ bnsc, int E)
{
    const int t = threadIdx.x;
    if (t < 4) {
        const float inv = 1.f / (float)E;
        const float mu  = bnstat[t] * inv;
        const float var = bnstat[4 + t] * inv - mu * mu;
        const float scl = gam[t] * rsqrtf(var + 1e-5f);
        bnsc[t] = scl;
        bnsc[4 + t] = bet[t] - mu * scl;
    }
}

// k3: alpha1 = sp(scale*alpha0+shift); segment max via uint atomicMax (alpha1>0)
__global__ __launch_bounds__(256) void k3_bnmax(
    float* __restrict__ alpha, const int* __restrict__ eidx,
    unsigned int* __restrict__ mbuf, const float* __restrict__ bnsc, int E)
{
    const int t = blockIdx.x * 256 + threadIdx.x;
    if (t >= 4 * E) return;
    const int e = t >> 2, h = t & 3;
    const float a1 = sp(bnsc[h] * alpha[t] + bnsc[4 + h]);
    alpha[t] = a1;
    atomicMax(&mbuf[eidx[e] * 4 + h], __float_as_uint(a1));
}

// k4: ex = exp(alpha1 - m[row]); segment sum
__global__ __launch_bounds__(256) void k4_exps(
    float* __restrict__ alpha, const int* __restrict__ eidx,
    const float* __restrict__ mbuf, float* __restrict__ sbuf, int E)
{
    const int t = blockIdx.x * 256 + threadIdx.x;
    if (t >= 4 * E) return;
    const int e = t >> 2, h = t & 3;
    const float ex = fexp(alpha[t] - mbuf[eidx[e] * 4 + h]);
    alpha[t] = ex;
    atomicAdd(&sbuf[eidx[e] * 4 + h], ex);
}

// ---------------------------------------------------------------------------
// kmsg: recompute Ee via MFMA; hj = sp(A[j]+Ee); out[i] += 0.25*sum_h af_h*hj
// A[j] gathered wide -> LDS as in kB.
// ---------------------------------------------------------------------------
__global__ __launch_bounds__(256) void kmsg(
    FP ef, const int* __restrict__ eidx, const short* __restrict__ Abf,
    FP We, const float* __restrict__ alpha, const float* __restrict__ sbuf,
    float* __restrict__ outacc, int E)
{
    __shared__ __align__(16) short As[4][16 * 136];   // 17.4 KB
    const int l = threadIdx.x & 63, q = l >> 4, e15 = l & 15, wvb = threadIdx.x >> 6;
    const int gr = l >> 4, gc = l & 15;
    short* Asw = As[wvb];
    const int wv = blockIdx.x * 4 + wvb, nw = gridDim.x * 4;
    bf16x8 wf[8];
#pragma unroll
    for (int mb = 0; mb < 8; ++mb) wf[mb] = load_wfrag(We, 128, 16 * mb, l);
    const f32x4 z = {0.f, 0.f, 0.f, 0.f};

    const int nt = E >> 4;
    for (int tt = wv; tt < nt; tt += nw) {
        const int tb = tt * 16;
#pragma unroll
        for (int g = 0; g < 4; ++g) {
            const int rsel = g * 4 + gr;
            const int node = eidx[E + tb + rsel];
            const float4 v = *(const float4*)&Abf[(size_t)node * 128 + gc * 8];
            *(float4*)&Asw[rsel * 136 + gc * 8] = v;
        }
        bf16x8 xf = load_xfrag32(ef, tb, l, E);
        f32x4 acc[8];
#pragma unroll
        for (int mb = 0; mb < 8; ++mb)
            acc[mb] = __builtin_amdgcn_mfma_f32_16x16x32_bf16(wf[mb], xf, z, 0, 0, 0);

        const int e = tb + e15;
        const int i = eidx[e];
        const float4 a4 = *(const float4*)&alpha[(size_t)e * 4];
        const float4 s4 = *(const float4*)&sbuf[(size_t)i * 4];
        float af[4];
#pragma unroll
        for (int h = 0; h < 4; ++h)
            af[h] = (&a4.x)[h] * __builtin_amdgcn_rcpf((&s4.x)[h] + 1e-16f);

        float c4[8] = {0,0,0,0,0,0,0,0};
#pragma unroll
        for (int p = 0; p < 4; ++p) {
            const bf16x8 Aj = *(const bf16x8*)&Asw[e15 * 136 + 32 * q + 8 * p];
#pragma unroll
            for (int jj = 0; jj < 8; ++jj)
                c4[jj] += sp(bf2f(Aj[jj]) + acc[2 * p + (jj >> 2)][jj & 3]) * af[p];
        }
#pragma unroll
        for (int jj = 0; jj < 8; ++jj) {
            const int c = (jj >> 2) * 16 + 4 * q + (jj & 3);
            atomicAdd(&outacc[(size_t)i * 32 + c], 0.25f * c4[jj]);
        }
    }
}

// kout: out += bias (acc accumulated in place in d_out)
__global__ __launch_bounds__(256) void kout(float* __restrict__ outp, FP bias, int N)
{
    const int t = blockIdx.x * 256 + threadIdx.x;
    if (t < N * 32) outp[t] += bias[t & 31];
}

// ---------------------------------------------------------------------------
// kG2: R = ef@W1c via MFMA -> LDS; P/Q rows gathered wide -> LDS;
// h = silu(P+Q+R+b1); eout = silu(h@W2 + b2) via MFMA.
// ---------------------------------------------------------------------------
__global__ __launch_bounds__(256) void kG2(
    FP ef, const int* __restrict__ eidx, const short* __restrict__ PQ,
    FP W1c, FP W2, FP b1g, FP b2g, float* __restrict__ eout, int E)
{
    __shared__ float b1l[128];
    __shared__ float b2l[32];
    __shared__ __align__(16) short Ps[4][32 * 136];   // 34.8 KB: 16 P-rows + 16 Q-rows
    __shared__ __align__(16) short Rl[4][16 * 136];   // 17.4 KB
    const int t = threadIdx.x;
    if (t < 128) b1l[t] = b1g[t];
    if (t < 32)  b2l[t] = b2g[t];
    __syncthreads();

    const int l = t & 63, q = l >> 4, e15 = l & 15, wvb = t >> 6;
    const int gr = l >> 4, gc = l & 15;
    short* Psw = Ps[wvb];
    short* Rw  = Rl[wvb];
    bf16x8 wr[8];
#pragma unroll
    for (int mb = 0; mb < 8; ++mb) wr[mb] = load_wfrag(W1c, 128, 16 * mb, l);
    bf16x8 w2f[4][2];
#pragma unroll
    for (int kc = 0; kc < 4; ++kc)
#pragma unroll
        for (int m2 = 0; m2 < 2; ++m2)
            w2f[kc][m2] = load_wfrag(W2 + 32 * kc * 32, 32, 16 * m2, l);
    const f32x4 z = {0.f, 0.f, 0.f, 0.f};

    const int wv = blockIdx.x * 4 + wvb, nw = gridDim.x * 4, nt = E >> 4;
    for (int tt = wv; tt < nt; tt += nw) {
        const int tb = tt * 16;
        // gather P rows (0..15) and Q rows (16..31), 256B each
#pragma unroll
        for (int g = 0; g < 8; ++g) {
            const int rsel = g * 4 + gr;
            const int hi = rsel >> 4;
            const int node = eidx[tb + (rsel & 15) + (hi ? E : 0)];
            const float4 v = *(const float4*)&PQ[(size_t)node * 256 + hi * 128 + gc * 8];
            *(float4*)&Psw[rsel * 136 + gc * 8] = v;
        }
        bf16x8 xf = load_xfrag32(ef, tb, l, E);
#pragma unroll
        for (int mb = 0; mb < 8; ++mb) {
            f32x4 c = __builtin_amdgcn_mfma_f32_16x16x32_bf16(wr[mb], xf, z, 0, 0, 0);
            short4 s = { f2bf(c[0]), f2bf(c[1]), f2bf(c[2]), f2bf(c[3]) };
            *(short4*)&Rw[e15 * 136 + 16 * mb + 4 * q] = s;
        }
        const int e = tb + e15;
        f32x4 oc0 = z, oc1 = z;
#pragma unroll
        for (int kc = 0; kc < 4; ++kc) {
            const int o = 32 * kc + 8 * q;
            const bf16x8 rv = *(const bf16x8*)&Rw[e15 * 136 + o];
            const bf16x8 pv = *(const bf16x8*)&Psw[e15 * 136 + o];
            const bf16x8 qv = *(const bf16x8*)&Psw[(16 + e15) * 136 + o];
            const float4 bA = *(const float4*)&b1l[o];
            const float4 bB = *(const float4*)&b1l[o + 4];
            bf16x8 hf;
#pragma unroll
            for (int jj = 0; jj < 4; ++jj) {
                hf[jj]     = f2bf(silu_f(bf2f(rv[jj])     + bf2f(pv[jj])     + bf2f(qv[jj])     + (&bA.x)[jj]));
                hf[4 + jj] = f2bf(silu_f(bf2f(rv[4 + jj]) + bf2f(pv[4 + jj]) + bf2f(qv[4 + jj]) + (&bB.x)[jj]));
            }
            oc0 = __builtin_amdgcn_mfma_f32_16x16x32_bf16(w2f[kc][0], hf, oc0, 0, 0, 0);
            oc1 = __builtin_amdgcn_mfma_f32_16x16x32_bf16(w2f[kc][1], hf, oc1, 0, 0, 0);
        }
        float4 o0, o1;
#pragma unroll
        for (int r = 0; r < 4; ++r) {
            (&o0.x)[r] = silu_f(oc0[r] + b2l[4 * q + r]);
            (&o1.x)[r] = silu_f(oc1[r] + b2l[16 + 4 * q + r]);
        }
        *(float4*)&eout[(size_t)e * 32 + 4 * q] = o0;
        *(float4*)&eout[(size_t)e * 32 + 16 + 4 * q] = o1;
    }
}

extern "C" void kernel_launch(void* const* d_in, const int* in_sizes, int n_in,
                              void* d_out, int out_size, void* d_ws, size_t ws_size,
                              hipStream_t stream)
{
    const float* atom = (const float*)d_in[0];
    const int*   eidx = (const int*)d_in[1];
    const float* efea = (const float*)d_in[2];
    const float* Wg   = (const float*)d_in[6];
    const float* attg = (const float*)d_in[7];
    const float* bias = (const float*)d_in[8];
    const float* gam  = (const float*)d_in[9];
    const float* bet  = (const float*)d_in[10];
    const float* W1g  = (const float*)d_in[11];
    const float* b1g  = (const float*)d_in[12];
    const float* W2g  = (const float*)d_in[13];
    const float* b2g  = (const float*)d_in[14];

    const int N = in_sizes[0] / 32;
    const int E = in_sizes[2] / 32;

    // workspace: mbuf[4N] sbuf[4N] bnstat[8] bnsc[8] PQ[N*256 bf16]
    float* ws     = (float*)d_ws;
    float* mbuf   = ws;
    float* sbuf   = ws + (size_t)4 * N;
    float* bnstat = ws + (size_t)8 * N;
    float* bnsc   = bnstat + 8;
    short* PQ     = (short*)(ws + (size_t)8 * N + 16);

    // d_out: [out N*32 f32][eout E*32 f32]; eout region doubles as scratch
    float* outp = (float*)d_out;
    float* scratch = outp + (size_t)N * 32;
    short* Abf  = (short*)scratch;                   // N*128 bf16
    float* alpha = scratch + (size_t)N * 64;         // 4E f32
    float* eout = scratch;                           // written last by kG2

    hipMemsetAsync(outp, 0, (size_t)N * 32 * sizeof(float), stream);       // msg accumulator
    hipMemsetAsync(ws, 0, ((size_t)8 * N + 16) * sizeof(float), stream);   // mbuf,sbuf,bnstat

    const int n4e = 4 * E;
    kA  <<<256, 256, 0, stream>>>(atom, Wg, Abf, N);
    kB  <<<2048, 256, 0, stream>>>(efea, eidx, Abf, Wg + 32 * 128, attg, alpha, bnstat, E);
    k2_bn<<<1, 64, 0, stream>>>(bnstat, gam, bet, bnsc, E);
    k3_bnmax<<<(n4e + 255) / 256, 256, 0, stream>>>(alpha, eidx, (unsigned int*)mbuf, bnsc, E);
    k4_exps <<<(n4e + 255) / 256, 256, 0, stream>>>(alpha, eidx, mbuf, sbuf, E);
    kmsg<<<2048, 256, 0, stream>>>(efea, eidx, Abf, Wg + 32 * 128, alpha, sbuf, outp, E);
    kout<<<(N * 32 + 255) / 256, 256, 0, stream>>>(outp, bias, N);
    kPQ <<<256, 256, 0, stream>>>(outp, W1g, PQ, N);
    kG2 <<<2048, 256, 0, stream>>>(efea, eidx, PQ, W1g + 64 * 128, W2g, b1g, b2g, eout, E);
}

// Round 6
// 1446.250 us; speedup vs baseline: 1.0440x; 1.0440x over previous
//
#include <hip/hip_runtime.h>

typedef __attribute__((ext_vector_type(8))) short bf16x8;
typedef __attribute__((ext_vector_type(4))) float f32x4;

#define FP const float* __restrict__

__device__ __forceinline__ short f2bf(float f) {
    unsigned u = __float_as_uint(f);
    u += 0x7fffu + ((u >> 16) & 1u);
    return (short)(u >> 16);
}
__device__ __forceinline__ float bf2f(short s) {
    return __uint_as_float(((unsigned)(unsigned short)s) << 16);
}
__device__ __forceinline__ float v_exp2(float x) { float r; asm("v_exp_f32 %0, %1" : "=v"(r) : "v"(x)); return r; }
__device__ __forceinline__ float v_log2(float x) { float r; asm("v_log_f32 %0, %1" : "=v"(r) : "v"(x)); return r; }

__device__ __forceinline__ float fexp(float x) { return v_exp2(1.44269504f * x); }
__device__ __forceinline__ float sp(float x) {         // softplus, branch-free
    return fmaxf(x, 0.f) + 0.69314718f * v_log2(1.f + v_exp2(-1.44269504f * fabsf(x)));
}
__device__ __forceinline__ float silu_f(float x) {
    return x * __builtin_amdgcn_rcpf(1.f + v_exp2(-1.44269504f * x));
}

// A-operand = W^T tile: lane l holds W[k, c0+(l&15)], k = 8*(l>>4)+j. W is [32+,ld] f32.
__device__ __forceinline__ bf16x8 load_wfrag(FP w, int ld, int c0, int l) {
    const int c = c0 + (l & 15);
    const int k0 = 8 * (l >> 4);
    bf16x8 f;
#pragma unroll
    for (int j = 0; j < 8; ++j) f[j] = f2bf(w[(k0 + j) * ld + c]);
    return f;
}
// B-operand = x^T tile: lane l holds x[r0+(l&15), 8*(l>>4)+j]; x is [R,32] f32 row-major.
__device__ __forceinline__ bf16x8 load_xfrag32(FP x, int r0, int l, int R) {
    int row = r0 + (l & 15);
    row = row < R ? row : R - 1;
    const float* p = x + (size_t)row * 32 + 8 * (l >> 4);
    const float4 a = *(const float4*)p;
    const float4 b = *(const float4*)(p + 4);
    bf16x8 f;
    f[0]=f2bf(a.x); f[1]=f2bf(a.y); f[2]=f2bf(a.z); f[3]=f2bf(a.w);
    f[4]=f2bf(b.x); f[5]=f2bf(b.y); f[6]=f2bf(b.z); f[7]=f2bf(b.w);
    return f;
}

// ---------------------------------------------------------------------------
// kA: A = bf16(atom @ Wa) [N,128], PERMUTED per row: short idx 32q+4mb+r
// ---------------------------------------------------------------------------
__global__ __launch_bounds__(256) void kA(FP x, FP W0, short* __restrict__ Aout, int R)
{
    const int l = threadIdx.x & 63;
    const int wv = blockIdx.x * 4 + (threadIdx.x >> 6);
    const int nw = gridDim.x * 4;
    bf16x8 wf[8];
#pragma unroll
    for (int mb = 0; mb < 8; ++mb) wf[mb] = load_wfrag(W0, 128, 16 * mb, l);
    const f32x4 z = {0.f, 0.f, 0.f, 0.f};
    const int nt = (R + 15) >> 4;
    for (int t = wv; t < nt; t += nw) {
        bf16x8 xf = load_xfrag32(x, t * 16, l, R);
        const int node = t * 16 + (l & 15);
        const int q = l >> 4;
#pragma unroll
        for (int mb = 0; mb < 8; ++mb) {
            f32x4 c = __builtin_amdgcn_mfma_f32_16x16x32_bf16(wf[mb], xf, z, 0, 0, 0);
            short4 s = { f2bf(c[0]), f2bf(c[1]), f2bf(c[2]), f2bf(c[3]) };
            if (node < R) *(short4*)&Aout[(size_t)node * 128 + 32 * q + 4 * mb] = s;
        }
    }
}

// ---------------------------------------------------------------------------
// kB: Ee = ef@We via MFMA; hi/hj = sp(A[i/j]+Ee); att dot -> alpha0 + BN stats
// Optionally stores hj (bf16, tile-major frags) for the streaming kmsg.
// ---------------------------------------------------------------------------
template<bool SHJ>
__global__ __launch_bounds__(256) void kBt(
    FP ef, const int* __restrict__ eidx, const short* __restrict__ Abf,
    FP We, FP attg, float* __restrict__ alpha, float* __restrict__ bnstat,
    short* __restrict__ hjt, int E)
{
    __shared__ float attl[256];
    const int t = threadIdx.x;
    if (t < 64) ((float4*)attl)[t] = ((const float4*)attg)[t];
    __syncthreads();

    const int l = t & 63, q = l >> 4, e15 = l & 15;
    const int wv = blockIdx.x * 4 + (t >> 6), nw = gridDim.x * 4;
    bf16x8 wf[8];
#pragma unroll
    for (int mb = 0; mb < 8; ++mb) wf[mb] = load_wfrag(We, 128, 16 * mb, l);
    const f32x4 z = {0.f, 0.f, 0.f, 0.f};
    float bs[4] = {0,0,0,0}, bq2[4] = {0,0,0,0};

    const int nt = E >> 4;
    for (int tt = wv; tt < nt; tt += nw) {
        const int tb = tt * 16;
        bf16x8 xf = load_xfrag32(ef, tb, l, E);
        f32x4 acc[8];
#pragma unroll
        for (int mb = 0; mb < 8; ++mb)
            acc[mb] = __builtin_amdgcn_mfma_f32_16x16x32_bf16(wf[mb], xf, z, 0, 0, 0);

        const int e = tb + e15;
        const int i = eidx[e], j = eidx[E + e];
        float ph[4] = {0,0,0,0};
#pragma unroll
        for (int p = 0; p < 4; ++p) {
            const bf16x8 Ai = *(const bf16x8*)&Abf[(size_t)i * 128 + 32 * q + 8 * p];
            const bf16x8 Aj = *(const bf16x8*)&Abf[(size_t)j * 128 + 32 * q + 8 * p];
            float hjv[8];
#pragma unroll
            for (int jj = 0; jj < 8; ++jj) {
                const float ev = acc[2 * p + (jj >> 2)][jj & 3];
                const int c = (jj >> 2) * 16 + 4 * q + (jj & 3);
                const float hj = sp(bf2f(Aj[jj]) + ev);
                hjv[jj] = hj;
                ph[p] += sp(bf2f(Ai[jj]) + ev) * attl[p * 64 + c]
                       + hj * attl[p * 64 + 32 + c];
            }
            if (SHJ) {
                // frag store: idx(tt,q,mb,e15,r) = (((tt*4+q)*8+mb)*16+e15)*4+r
                const size_t b0 = (((size_t)tt * 4 + q) * 8 + 2 * p) * 64 + e15 * 4;
                short4 s0 = { f2bf(hjv[0]), f2bf(hjv[1]), f2bf(hjv[2]), f2bf(hjv[3]) };
                short4 s1 = { f2bf(hjv[4]), f2bf(hjv[5]), f2bf(hjv[6]), f2bf(hjv[7]) };
                *(short4*)&hjt[b0] = s0;
                *(short4*)&hjt[b0 + 64] = s1;
            }
        }
        float4 a0v;
#pragma unroll
        for (int h = 0; h < 4; ++h) {
            float v = ph[h];
            v += __shfl_xor(v, 16);
            v += __shfl_xor(v, 32);
            (&a0v.x)[h] = sp(v);
        }
        if (q == 0) {
            *(float4*)&alpha[(size_t)e * 4] = a0v;
#pragma unroll
            for (int h = 0; h < 4; ++h) {
                const float a0 = (&a0v.x)[h];
                bs[h] += a0; bq2[h] += a0 * a0;
            }
        }
    }
#pragma unroll
    for (int h = 0; h < 4; ++h) {
        float v = bs[h], w = bq2[h];
#pragma unroll
        for (int d = 1; d < 64; d <<= 1) { v += __shfl_xor(v, d); w += __shfl_xor(w, d); }
        if (l == 0) { atomicAdd(&bnstat[h], v); atomicAdd(&bnstat[4 + h], w); }
    }
}

// k2: finalize BN scale/shift
__global__ void k2_bn(const float* __restrict__ bnstat, FP gam, FP bet,
                      float* __restrict__ bnsc, int E)
{
    const int t = threadIdx.x;
    if (t < 4) {
        const float inv = 1.f / (float)E;
        const float mu  = bnstat[t] * inv;
        const float var = bnstat[4 + t] * inv - mu * mu;
        const float scl = gam[t] * rsqrtf(var + 1e-5f);
        bnsc[t] = scl;
        bnsc[4 + t] = bet[t] - mu * scl;
    }
}

// k3: alpha1 = sp(scale*alpha0+shift); segment max via uint atomicMax (alpha1>0)
__global__ __launch_bounds__(256) void k3_bnmax(
    float* __restrict__ alpha, const int* __restrict__ eidx,
    unsigned int* __restrict__ mbuf, const float* __restrict__ bnsc, int E)
{
    const int t = blockIdx.x * 256 + threadIdx.x;
    if (t >= 4 * E) return;
    const int e = t >> 2, h = t & 3;
    const float a1 = sp(bnsc[h] * alpha[t] + bnsc[4 + h]);
    alpha[t] = a1;
    atomicMax(&mbuf[eidx[e] * 4 + h], __float_as_uint(a1));
}

// k4: ex = exp(alpha1 - m[row]); segment sum
__global__ __launch_bounds__(256) void k4_exps(
    float* __restrict__ alpha, const int* __restrict__ eidx,
    const float* __restrict__ mbuf, float* __restrict__ sbuf, int E)
{
    const int t = blockIdx.x * 256 + threadIdx.x;
    if (t >= 4 * E) return;
    const int e = t >> 2, h = t & 3;
    const float ex = fexp(alpha[t] - mbuf[eidx[e] * 4 + h]);
    alpha[t] = ex;
    atomicAdd(&sbuf[eidx[e] * 4 + h], ex);
}

// ---------------------------------------------------------------------------
// kmsg_s: streaming message pass: out[i] += 0.25*sum_h af_h * hj[h,:]
// hj read back in the exact tile-major frag layout kB stored.
// ---------------------------------------------------------------------------
__global__ __launch_bounds__(256) void kmsg_s(
    const int* __restrict__ eidx, const short* __restrict__ hjt,
    const float* __restrict__ alpha, const float* __restrict__ sbuf,
    float* __restrict__ outacc, int E)
{
    const int l = threadIdx.x & 63, q = l >> 4, e15 = l & 15;
    const int wv = blockIdx.x * 4 + (threadIdx.x >> 6), nw = gridDim.x * 4;
    const int nt = E >> 4;
    for (int tt = wv; tt < nt; tt += nw) {
        const int e = tt * 16 + e15;
        const int i = eidx[e];
        const float4 a4 = *(const float4*)&alpha[(size_t)e * 4];
        const float4 s4 = *(const float4*)&sbuf[(size_t)i * 4];
        float af[4];
#pragma unroll
        for (int h = 0; h < 4; ++h)
            af[h] = (&a4.x)[h] * __builtin_amdgcn_rcpf((&s4.x)[h] + 1e-16f);

        float c4[8] = {0,0,0,0,0,0,0,0};
#pragma unroll
        for (int mb = 0; mb < 8; ++mb) {
            const short4 hv = *(const short4*)&hjt[(((size_t)tt * 4 + q) * 8 + mb) * 64 + e15 * 4];
            const float a = af[mb >> 1];
            const int s = (mb & 1) * 4;
            c4[s + 0] += a * bf2f(hv.x);
            c4[s + 1] += a * bf2f(hv.y);
            c4[s + 2] += a * bf2f(hv.z);
            c4[s + 3] += a * bf2f(hv.w);
        }
#pragma unroll
        for (int s2 = 0; s2 < 2; ++s2)
#pragma unroll
            for (int r = 0; r < 4; ++r)
                atomicAdd(&outacc[(size_t)i * 32 + s2 * 16 + 4 * q + r], 0.25f * c4[s2 * 4 + r]);
    }
}

// kmsg_re: fallback (ws too small): recompute Ee + gather A[j]
__global__ __launch_bounds__(256) void kmsg_re(
    FP ef, const int* __restrict__ eidx, const short* __restrict__ Abf,
    FP We, const float* __restrict__ alpha, const float* __restrict__ sbuf,
    float* __restrict__ outacc, int E)
{
    const int l = threadIdx.x & 63, q = l >> 4, e15 = l & 15;
    const int wv = blockIdx.x * 4 + (threadIdx.x >> 6), nw = gridDim.x * 4;
    bf16x8 wf[8];
#pragma unroll
    for (int mb = 0; mb < 8; ++mb) wf[mb] = load_wfrag(We, 128, 16 * mb, l);
    const f32x4 z = {0.f, 0.f, 0.f, 0.f};
    const int nt = E >> 4;
    for (int tt = wv; tt < nt; tt += nw) {
        bf16x8 xf = load_xfrag32(ef, tt * 16, l, E);
        f32x4 acc[8];
#pragma unroll
        for (int mb = 0; mb < 8; ++mb)
            acc[mb] = __builtin_amdgcn_mfma_f32_16x16x32_bf16(wf[mb], xf, z, 0, 0, 0);
        const int e = tt * 16 + e15;
        const int i = eidx[e], j = eidx[E + e];
        const float4 a4 = *(const float4*)&alpha[(size_t)e * 4];
        const float4 s4 = *(const float4*)&sbuf[(size_t)i * 4];
        float af[4];
#pragma unroll
        for (int h = 0; h < 4; ++h)
            af[h] = (&a4.x)[h] * __builtin_amdgcn_rcpf((&s4.x)[h] + 1e-16f);
        float c4[8] = {0,0,0,0,0,0,0,0};
#pragma unroll
        for (int p = 0; p < 4; ++p) {
            const bf16x8 Aj = *(const bf16x8*)&Abf[(size_t)j * 128 + 32 * q + 8 * p];
#pragma unroll
            for (int jj = 0; jj < 8; ++jj)
                c4[jj] += sp(bf2f(Aj[jj]) + acc[2 * p + (jj >> 2)][jj & 3]) * af[p];
        }
#pragma unroll
        for (int jj = 0; jj < 8; ++jj) {
            const int c = (jj >> 2) * 16 + 4 * q + (jj & 3);
            atomicAdd(&outacc[(size_t)i * 32 + c], 0.25f * c4[jj]);
        }
    }
}

// kout: out += bias
__global__ __launch_bounds__(256) void kout(float* __restrict__ outp, FP bias, int N)
{
    const int t = blockIdx.x * 256 + threadIdx.x;
    if (t < N * 32) outp[t] += bias[t & 31];
}

// ---------------------------------------------------------------------------
// kG2n: direct edge MLP. x = [out[row] | out[col] | ef] (K=96, 3 MFMA k-steps,
// W1 frags in LDS); h = silu(.+b1) -> LDS bounce -> eout = silu(h@W2+b2).
// ---------------------------------------------------------------------------
__global__ __launch_bounds__(256) void kG2n(
    FP ef, const int* __restrict__ eidx, FP outp,
    FP W1g, FP W2, FP b1g, FP b2g, float* __restrict__ eout, int E)
{
    __shared__ __align__(16) short W1f[3][8][64][8];   // 24 KB, frag layout
    __shared__ float b1l[128];
    __shared__ float b2l[32];
    __shared__ __align__(16) short hs[4][16 * 132];    // 16.9 KB h-bounce
    const int t = threadIdx.x;
    for (int s = t; s < 3 * 8 * 64; s += 256) {
        const int ks = s >> 9, rem = s & 511, mb = rem >> 6, ll = rem & 63;
        const int c = 16 * mb + (ll & 15);
        const int k0 = ks * 32 + 8 * (ll >> 4);
        bf16x8 f;
#pragma unroll
        for (int j = 0; j < 8; ++j) f[j] = f2bf(W1g[(size_t)(k0 + j) * 128 + c]);
        *(bf16x8*)&W1f[ks][mb][ll][0] = f;
    }
    if (t < 128) b1l[t] = b1g[t];
    if (t < 32)  b2l[t] = b2g[t];
    __syncthreads();

    const int l = t & 63, q = l >> 4, e15 = l & 15, wvb = t >> 6;
    short* hw = &hs[wvb][0];
    bf16x8 w2f[4][2];
#pragma unroll
    for (int kc = 0; kc < 4; ++kc)
#pragma unroll
        for (int m2 = 0; m2 < 2; ++m2)
            w2f[kc][m2] = load_wfrag(W2 + 32 * kc * 32, 32, 16 * m2, l);
    const f32x4 z = {0.f, 0.f, 0.f, 0.f};

    const int wv = blockIdx.x * 4 + wvb, nw = gridDim.x * 4, nt = E >> 4;
    for (int tt = wv; tt < nt; tt += nw) {
        const int tb = tt * 16;
        const int e = tb + e15;
        const int ri = eidx[e], ci = eidx[E + e];
        bf16x8 xb[3];
        {   // out[row] slice: lane covers cols 8q..8q+7 of its edge's row
            const float* p = outp + (size_t)ri * 32 + 8 * q;
            const float4 a = *(const float4*)p; const float4 b = *(const float4*)(p + 4);
            xb[0][0]=f2bf(a.x); xb[0][1]=f2bf(a.y); xb[0][2]=f2bf(a.z); xb[0][3]=f2bf(a.w);
            xb[0][4]=f2bf(b.x); xb[0][5]=f2bf(b.y); xb[0][6]=f2bf(b.z); xb[0][7]=f2bf(b.w);
        }
        {   // out[col]
            const float* p = outp + (size_t)ci * 32 + 8 * q;
            const float4 a = *(const float4*)p; const float4 b = *(const float4*)(p + 4);
            xb[1][0]=f2bf(a.x); xb[1][1]=f2bf(a.y); xb[1][2]=f2bf(a.z); xb[1][3]=f2bf(a.w);
            xb[1][4]=f2bf(b.x); xb[1][5]=f2bf(b.y); xb[1][6]=f2bf(b.z); xb[1][7]=f2bf(b.w);
        }
        xb[2] = load_xfrag32(ef, tb, l, E);

        f32x4 a1[8] = {z, z, z, z, z, z, z, z};
#pragma unroll
        for (int ks = 0; ks < 3; ++ks)
#pragma unroll
            for (int mb = 0; mb < 8; ++mb) {
                const bf16x8 wfr = *(const bf16x8*)&W1f[ks][mb][l][0];
                a1[mb] = __builtin_amdgcn_mfma_f32_16x16x32_bf16(wfr, xb[ks], a1[mb], 0, 0, 0);
            }
        // silu + bounce into B-frag layout
#pragma unroll
        for (int mb = 0; mb < 8; ++mb) {
            short4 s;
            s.x = f2bf(silu_f(a1[mb][0] + b1l[16 * mb + 4 * q + 0]));
            s.y = f2bf(silu_f(a1[mb][1] + b1l[16 * mb + 4 * q + 1]));
            s.z = f2bf(silu_f(a1[mb][2] + b1l[16 * mb + 4 * q + 2]));
            s.w = f2bf(silu_f(a1[mb][3] + b1l[16 * mb + 4 * q + 3]));
            *(short4*)&hw[e15 * 132 + 16 * mb + 4 * q] = s;
        }
        f32x4 oc0 = z, oc1 = z;
#pragma unroll
        for (int kc = 0; kc < 4; ++kc) {
            const bf16x8 hf = *(const bf16x8*)&hw[e15 * 132 + kc * 32 + 8 * q];
            oc0 = __builtin_amdgcn_mfma_f32_16x16x32_bf16(w2f[kc][0], hf, oc0, 0, 0, 0);
            oc1 = __builtin_amdgcn_mfma_f32_16x16x32_bf16(w2f[kc][1], hf, oc1, 0, 0, 0);
        }
        float4 o0, o1;
#pragma unroll
        for (int r = 0; r < 4; ++r) {
            (&o0.x)[r] = silu_f(oc0[r] + b2l[4 * q + r]);
            (&o1.x)[r] = silu_f(oc1[r] + b2l[16 + 4 * q + r]);
        }
        *(float4*)&eout[(size_t)e * 32 + 4 * q] = o0;
        *(float4*)&eout[(size_t)e * 32 + 16 + 4 * q] = o1;
    }
}

extern "C" void kernel_launch(void* const* d_in, const int* in_sizes, int n_in,
                              void* d_out, int out_size, void* d_ws, size_t ws_size,
                              hipStream_t stream)
{
    const float* atom = (const float*)d_in[0];
    const int*   eidx = (const int*)d_in[1];
    const float* efea = (const float*)d_in[2];
    const float* Wg   = (const float*)d_in[6];
    const float* attg = (const float*)d_in[7];
    const float* bias = (const float*)d_in[8];
    const float* gam  = (const float*)d_in[9];
    const float* bet  = (const float*)d_in[10];
    const float* W1g  = (const float*)d_in[11];
    const float* b1g  = (const float*)d_in[12];
    const float* W2g  = (const float*)d_in[13];
    const float* b2g  = (const float*)d_in[14];

    const int N = in_sizes[0] / 32;
    const int E = in_sizes[2] / 32;

    // workspace: mbuf[4N] sbuf[4N] bnstat[8] bnsc[8] hjt[E*128 bf16]
    float* ws     = (float*)d_ws;
    float* mbuf   = ws;
    float* sbuf   = ws + (size_t)4 * N;
    float* bnstat = ws + (size_t)8 * N;
    float* bnsc   = bnstat + 8;
    short* hjt    = (short*)(ws + (size_t)8 * N + 16);
    const size_t ws_need = ((size_t)8 * N + 16) * 4 + (size_t)E * 128 * 2;
    const bool use_hj = ws_size >= ws_need;

    // d_out: [out N*32 f32][eout E*32 f32]; eout region doubles as scratch
    float* outp = (float*)d_out;
    float* scratch = outp + (size_t)N * 32;
    short* Abf  = (short*)scratch;                   // N*128 bf16
    float* alpha = scratch + (size_t)N * 64;         // 4E f32
    float* eout = scratch;                           // written last by kG2n

    hipMemsetAsync(outp, 0, (size_t)N * 32 * sizeof(float), stream);
    hipMemsetAsync(ws, 0, ((size_t)8 * N + 16) * sizeof(float), stream);

    const int n4e = 4 * E;
    kA<<<256, 256, 0, stream>>>(atom, Wg, Abf, N);
    if (use_hj)
        kBt<true><<<2048, 256, 0, stream>>>(efea, eidx, Abf, Wg + 32 * 128, attg, alpha, bnstat, hjt, E);
    else
        kBt<false><<<2048, 256, 0, stream>>>(efea, eidx, Abf, Wg + 32 * 128, attg, alpha, bnstat, hjt, E);
    k2_bn<<<1, 64, 0, stream>>>(bnstat, gam, bet, bnsc, E);
    k3_bnmax<<<(n4e + 255) / 256, 256, 0, stream>>>(alpha, eidx, (unsigned int*)mbuf, bnsc, E);
    k4_exps <<<(n4e + 255) / 256, 256, 0, stream>>>(alpha, eidx, mbuf, sbuf, E);
    if (use_hj)
        kmsg_s<<<2048, 256, 0, stream>>>(eidx, hjt, alpha, sbuf, outp, E);
    else
        kmsg_re<<<2048, 256, 0, stream>>>(efea, eidx, Abf, Wg + 32 * 128, alpha, sbuf, outp, E);
    kout<<<(N * 32 + 255) / 256, 256, 0, stream>>>(outp, bias, N);
    kG2n<<<2048, 256, 0, stream>>>(efea, eidx, outp, W1g, W2g, b1g, b2g, eout, E);
}

// Round 7
// 1414.633 us; speedup vs baseline: 1.0673x; 1.0224x over previous
//
#include <hip/hip_runtime.h>

typedef __attribute__((ext_vector_type(8))) short bf16x8;
typedef __attribute__((ext_vector_type(4))) float f32x4;

#define FP const float* __restrict__

__device__ __forceinline__ short f2bf(float f) {
    unsigned u = __float_as_uint(f);
    u += 0x7fffu + ((u >> 16) & 1u);
    return (short)(u >> 16);
}
__device__ __forceinline__ float bf2f(short s) {
    return __uint_as_float(((unsigned)(unsigned short)s) << 16);
}
__device__ __forceinline__ float v_exp2(float x) { float r; asm("v_exp_f32 %0, %1" : "=v"(r) : "v"(x)); return r; }
__device__ __forceinline__ float v_log2(float x) { float r; asm("v_log_f32 %0, %1" : "=v"(r) : "v"(x)); return r; }

__device__ __forceinline__ float fexp(float x) { return v_exp2(1.44269504f * x); }
__device__ __forceinline__ float sp(float x) {         // softplus, branch-free
    return fmaxf(x, 0.f) + 0.69314718f * v_log2(1.f + v_exp2(-1.44269504f * fabsf(x)));
}
__device__ __forceinline__ float silu_f(float x) {
    return x * __builtin_amdgcn_rcpf(1.f + v_exp2(-1.44269504f * x));
}

// A-operand = W^T tile: lane l holds W[k, c0+(l&15)], k = 8*(l>>4)+j. W is [32+,ld] f32.
__device__ __forceinline__ bf16x8 load_wfrag(FP w, int ld, int c0, int l) {
    const int c = c0 + (l & 15);
    const int k0 = 8 * (l >> 4);
    bf16x8 f;
#pragma unroll
    for (int j = 0; j < 8; ++j) f[j] = f2bf(w[(k0 + j) * ld + c]);
    return f;
}

// ---------------------------------------------------------------------------
// kprep: bf16-ize atom (N*32) and ef (E*32), float4 -> short4 streaming
// ---------------------------------------------------------------------------
__global__ __launch_bounds__(256) void kprep(
    FP atom, FP ef, short* __restrict__ atomb, short* __restrict__ efb,
    int nA4, int nE4)
{
    const int stride = gridDim.x * 256;
    for (int t = blockIdx.x * 256 + threadIdx.x; t < nA4 + nE4; t += stride) {
        float4 v;
        short4 s;
        if (t < nA4) {
            v = ((const float4*)atom)[t];
            s.x = f2bf(v.x); s.y = f2bf(v.y); s.z = f2bf(v.z); s.w = f2bf(v.w);
            ((short4*)atomb)[t] = s;
        } else {
            v = ((const float4*)ef)[t - nA4];
            s.x = f2bf(v.x); s.y = f2bf(v.y); s.z = f2bf(v.z); s.w = f2bf(v.w);
            ((short4*)efb)[t - nA4] = s;
        }
    }
}

// ---------------------------------------------------------------------------
// kBv: per 16-edge tile, all in-register:
//   Ee = ef@We, Ha = atom[i]@Wa, Hb = atom[j]@Wa  (24 MFMAs)
//   hi=sp(Ha+Ee), hj=sp(Hb+Ee); att dot -> alpha0[E,4]; BN stats.
// atomb table is 3.2 MB -> per-XCD L2 resident; gathers are 16B/lane.
// ---------------------------------------------------------------------------
__global__ __launch_bounds__(256) void kBv(
    const short* __restrict__ efb, const int* __restrict__ eidx,
    const short* __restrict__ atomb, FP Wg, FP attg,
    float* __restrict__ alpha, float* __restrict__ bnstat, int E)
{
    __shared__ float attl[256];
    const int t = threadIdx.x;
    if (t < 64) ((float4*)attl)[t] = ((const float4*)attg)[t];
    __syncthreads();

    const int l = t & 63, q = l >> 4, e15 = l & 15;
    const int wv = blockIdx.x * 4 + (t >> 6), nw = gridDim.x * 4;
    bf16x8 wfa[8], wfe[8];
#pragma unroll
    for (int mb = 0; mb < 8; ++mb) {
        wfa[mb] = load_wfrag(Wg, 128, 16 * mb, l);            // rows 0..31 (atom)
        wfe[mb] = load_wfrag(Wg + 32 * 128, 128, 16 * mb, l); // rows 32..63 (edge)
    }
    const f32x4 z = {0.f, 0.f, 0.f, 0.f};
    float bs[4] = {0,0,0,0}, bq2[4] = {0,0,0,0};

    const int nt = E >> 4;
    for (int tt = wv; tt < nt; tt += nw) {
        const int tb = tt * 16;
        const int e = tb + e15;
        const int i = eidx[e], j = eidx[E + e];
        const bf16x8 xi = *(const bf16x8*)&atomb[(size_t)i * 32 + 8 * q];
        const bf16x8 xj = *(const bf16x8*)&atomb[(size_t)j * 32 + 8 * q];
        const bf16x8 xe = *(const bf16x8*)&efb[(size_t)e * 32 + 8 * q];

        float ph[4] = {0,0,0,0};
#pragma unroll
        for (int mb = 0; mb < 8; ++mb) {
            const f32x4 ee = __builtin_amdgcn_mfma_f32_16x16x32_bf16(wfe[mb], xe, z, 0, 0, 0);
            const f32x4 ha = __builtin_amdgcn_mfma_f32_16x16x32_bf16(wfa[mb], xi, z, 0, 0, 0);
            const f32x4 hb = __builtin_amdgcn_mfma_f32_16x16x32_bf16(wfa[mb], xj, z, 0, 0, 0);
            const int h = mb >> 1;
            const int c0 = (mb & 1) * 16 + 4 * q;
#pragma unroll
            for (int r = 0; r < 4; ++r) {
                ph[h] += sp(ha[r] + ee[r]) * attl[h * 64 + c0 + r]
                       + sp(hb[r] + ee[r]) * attl[h * 64 + 32 + c0 + r];
            }
        }
        float4 a0v;
#pragma unroll
        for (int h = 0; h < 4; ++h) {
            float v = ph[h];
            v += __shfl_xor(v, 16);
            v += __shfl_xor(v, 32);
            (&a0v.x)[h] = sp(v);
        }
        if (q == 0) {
            *(float4*)&alpha[(size_t)e * 4] = a0v;
#pragma unroll
            for (int h = 0; h < 4; ++h) {
                const float a0 = (&a0v.x)[h];
                bs[h] += a0; bq2[h] += a0 * a0;
            }
        }
    }
#pragma unroll
    for (int h = 0; h < 4; ++h) {
        float v = bs[h], w = bq2[h];
#pragma unroll
        for (int d = 1; d < 64; d <<= 1) { v += __shfl_xor(v, d); w += __shfl_xor(w, d); }
        if (l == 0) { atomicAdd(&bnstat[h], v); atomicAdd(&bnstat[4 + h], w); }
    }
}

// k2: finalize BN scale/shift
__global__ void k2_bn(const float* __restrict__ bnstat, FP gam, FP bet,
                      float* __restrict__ bnsc, int E)
{
    const int t = threadIdx.x;
    if (t < 4) {
        const float inv = 1.f / (float)E;
        const float mu  = bnstat[t] * inv;
        const float var = bnstat[4 + t] * inv - mu * mu;
        const float scl = gam[t] * rsqrtf(var + 1e-5f);
        bnsc[t] = scl;
        bnsc[4 + t] = bet[t] - mu * scl;
    }
}

// k3: alpha1 = sp(scale*alpha0+shift); segment max via uint atomicMax (alpha1>0)
__global__ __launch_bounds__(256) void k3_bnmax(
    float* __restrict__ alpha, const int* __restrict__ eidx,
    unsigned int* __restrict__ mbuf, const float* __restrict__ bnsc, int E)
{
    const int t = blockIdx.x * 256 + threadIdx.x;
    if (t >= 4 * E) return;
    const int e = t >> 2, h = t & 3;
    const float a1 = sp(bnsc[h] * alpha[t] + bnsc[4 + h]);
    alpha[t] = a1;
    atomicMax(&mbuf[eidx[e] * 4 + h], __float_as_uint(a1));
}

// k4: ex = exp(alpha1 - m[row]); segment sum
__global__ __launch_bounds__(256) void k4_exps(
    float* __restrict__ alpha, const int* __restrict__ eidx,
    const float* __restrict__ mbuf, float* __restrict__ sbuf, int E)
{
    const int t = blockIdx.x * 256 + threadIdx.x;
    if (t >= 4 * E) return;
    const int e = t >> 2, h = t & 3;
    const float ex = fexp(alpha[t] - mbuf[eidx[e] * 4 + h]);
    alpha[t] = ex;
    atomicAdd(&sbuf[eidx[e] * 4 + h], ex);
}

// ---------------------------------------------------------------------------
// kmsgv: recompute Ee + Hb (16 MFMAs); hj = sp(Hb+Ee);
//        out[i] += 0.25*sum_h af_h * hj[h,:]
// ---------------------------------------------------------------------------
__global__ __launch_bounds__(256) void kmsgv(
    const short* __restrict__ efb, const int* __restrict__ eidx,
    const short* __restrict__ atomb, FP Wg,
    const float* __restrict__ alpha, const float* __restrict__ sbuf,
    float* __restrict__ outacc, int E)
{
    const int l = threadIdx.x & 63, q = l >> 4, e15 = l & 15;
    const int wv = blockIdx.x * 4 + (threadIdx.x >> 6), nw = gridDim.x * 4;
    bf16x8 wfa[8], wfe[8];
#pragma unroll
    for (int mb = 0; mb < 8; ++mb) {
        wfa[mb] = load_wfrag(Wg, 128, 16 * mb, l);
        wfe[mb] = load_wfrag(Wg + 32 * 128, 128, 16 * mb, l);
    }
    const f32x4 z = {0.f, 0.f, 0.f, 0.f};

    const int nt = E >> 4;
    for (int tt = wv; tt < nt; tt += nw) {
        const int tb = tt * 16;
        const int e = tb + e15;
        const int i = eidx[e], j = eidx[E + e];
        const bf16x8 xj = *(const bf16x8*)&atomb[(size_t)j * 32 + 8 * q];
        const bf16x8 xe = *(const bf16x8*)&efb[(size_t)e * 32 + 8 * q];
        const float4 a4 = *(const float4*)&alpha[(size_t)e * 4];
        const float4 s4 = *(const float4*)&sbuf[(size_t)i * 4];
        float af[4];
#pragma unroll
        for (int h = 0; h < 4; ++h)
            af[h] = (&a4.x)[h] * __builtin_amdgcn_rcpf((&s4.x)[h] + 1e-16f);

        float c4[8] = {0,0,0,0,0,0,0,0};
#pragma unroll
        for (int mb = 0; mb < 8; ++mb) {
            const f32x4 ee = __builtin_amdgcn_mfma_f32_16x16x32_bf16(wfe[mb], xe, z, 0, 0, 0);
            const f32x4 hb = __builtin_amdgcn_mfma_f32_16x16x32_bf16(wfa[mb], xj, z, 0, 0, 0);
            const float a = af[mb >> 1];
            const int s = (mb & 1) * 4;
#pragma unroll
            for (int r = 0; r < 4; ++r)
                c4[s + r] += sp(hb[r] + ee[r]) * a;
        }
#pragma unroll
        for (int s2 = 0; s2 < 2; ++s2)
#pragma unroll
            for (int r = 0; r < 4; ++r)
                atomicAdd(&outacc[(size_t)i * 32 + s2 * 16 + 4 * q + r], 0.25f * c4[s2 * 4 + r]);
    }
}

// kout: out += bias; also write bf16 copy for the edge-MLP gathers
__global__ __launch_bounds__(256) void kout(
    float* __restrict__ outp, FP bias, short* __restrict__ outb, int N)
{
    const int t = blockIdx.x * 256 + threadIdx.x;
    if (t < N * 32) {
        const float v = outp[t] + bias[t & 31];
        outp[t] = v;
        outb[t] = f2bf(v);
    }
}

// ---------------------------------------------------------------------------
// kG2v: edge MLP. x = [outb[row] | outb[col] | efb] (K=96, 3 MFMA k-steps,
// W1 frags in LDS); h = silu(.+b1) -> LDS bounce -> eout = silu(h@W2+b2).
// outb table 3.2 MB -> L2 resident.
// ---------------------------------------------------------------------------
__global__ __launch_bounds__(256) void kG2v(
    const short* __restrict__ efb, const int* __restrict__ eidx,
    const short* __restrict__ outb,
    FP W1g, FP W2, FP b1g, FP b2g, float* __restrict__ eout, int E)
{
    __shared__ __align__(16) short W1f[3][8][64][8];   // 24 KB, frag layout
    __shared__ float b1l[128];
    __shared__ float b2l[32];
    __shared__ __align__(16) short hs[4][16 * 132];    // 16.9 KB h-bounce
    const int t = threadIdx.x;
    for (int s = t; s < 3 * 8 * 64; s += 256) {
        const int ks = s >> 9, rem = s & 511, mb = rem >> 6, ll = rem & 63;
        const int c = 16 * mb + (ll & 15);
        const int k0 = ks * 32 + 8 * (ll >> 4);
        bf16x8 f;
#pragma unroll
        for (int j = 0; j < 8; ++j) f[j] = f2bf(W1g[(size_t)(k0 + j) * 128 + c]);
        *(bf16x8*)&W1f[ks][mb][ll][0] = f;
    }
    if (t < 128) b1l[t] = b1g[t];
    if (t < 32)  b2l[t] = b2g[t];
    __syncthreads();

    const int l = t & 63, q = l >> 4, e15 = l & 15, wvb = t >> 6;
    short* hw = &hs[wvb][0];
    bf16x8 w2f[4][2];
#pragma unroll
    for (int kc = 0; kc < 4; ++kc)
#pragma unroll
        for (int m2 = 0; m2 < 2; ++m2)
            w2f[kc][m2] = load_wfrag(W2 + 32 * kc * 32, 32, 16 * m2, l);
    const f32x4 z = {0.f, 0.f, 0.f, 0.f};

    const int wv = blockIdx.x * 4 + wvb, nw = gridDim.x * 4, nt = E >> 4;
    for (int tt = wv; tt < nt; tt += nw) {
        const int tb = tt * 16;
        const int e = tb + e15;
        const int ri = eidx[e], ci = eidx[E + e];
        bf16x8 xb[3];
        xb[0] = *(const bf16x8*)&outb[(size_t)ri * 32 + 8 * q];
        xb[1] = *(const bf16x8*)&outb[(size_t)ci * 32 + 8 * q];
        xb[2] = *(const bf16x8*)&efb[(size_t)e * 32 + 8 * q];

        f32x4 a1[8] = {z, z, z, z, z, z, z, z};
#pragma unroll
        for (int ks = 0; ks < 3; ++ks)
#pragma unroll
            for (int mb = 0; mb < 8; ++mb) {
                const bf16x8 wfr = *(const bf16x8*)&W1f[ks][mb][l][0];
                a1[mb] = __builtin_amdgcn_mfma_f32_16x16x32_bf16(wfr, xb[ks], a1[mb], 0, 0, 0);
            }
        // silu + bounce into B-frag layout
#pragma unroll
        for (int mb = 0; mb < 8; ++mb) {
            short4 s;
            s.x = f2bf(silu_f(a1[mb][0] + b1l[16 * mb + 4 * q + 0]));
            s.y = f2bf(silu_f(a1[mb][1] + b1l[16 * mb + 4 * q + 1]));
            s.z = f2bf(silu_f(a1[mb][2] + b1l[16 * mb + 4 * q + 2]));
            s.w = f2bf(silu_f(a1[mb][3] + b1l[16 * mb + 4 * q + 3]));
            *(short4*)&hw[e15 * 132 + 16 * mb + 4 * q] = s;
        }
        f32x4 oc0 = z, oc1 = z;
#pragma unroll
        for (int kc = 0; kc < 4; ++kc) {
            const bf16x8 hf = *(const bf16x8*)&hw[e15 * 132 + kc * 32 + 8 * q];
            oc0 = __builtin_amdgcn_mfma_f32_16x16x32_bf16(w2f[kc][0], hf, oc0, 0, 0, 0);
            oc1 = __builtin_amdgcn_mfma_f32_16x16x32_bf16(w2f[kc][1], hf, oc1, 0, 0, 0);
        }
        float4 o0, o1;
#pragma unroll
        for (int r = 0; r < 4; ++r) {
            (&o0.x)[r] = silu_f(oc0[r] + b2l[4 * q + r]);
            (&o1.x)[r] = silu_f(oc1[r] + b2l[16 + 4 * q + r]);
        }
        *(float4*)&eout[(size_t)e * 32 + 4 * q] = o0;
        *(float4*)&eout[(size_t)e * 32 + 16 + 4 * q] = o1;
    }
}

extern "C" void kernel_launch(void* const* d_in, const int* in_sizes, int n_in,
                              void* d_out, int out_size, void* d_ws, size_t ws_size,
                              hipStream_t stream)
{
    const float* atom = (const float*)d_in[0];
    const int*   eidx = (const int*)d_in[1];
    const float* efea = (const float*)d_in[2];
    const float* Wg   = (const float*)d_in[6];
    const float* attg = (const float*)d_in[7];
    const float* bias = (const float*)d_in[8];
    const float* gam  = (const float*)d_in[9];
    const float* bet  = (const float*)d_in[10];
    const float* W1g  = (const float*)d_in[11];
    const float* b1g  = (const float*)d_in[12];
    const float* W2g  = (const float*)d_in[13];
    const float* b2g  = (const float*)d_in[14];

    const int N = in_sizes[0] / 32;
    const int E = in_sizes[2] / 32;

    // workspace layout
    float* ws     = (float*)d_ws;
    float* mbuf   = ws;                               // 4N f32
    float* sbuf   = ws + (size_t)4 * N;               // 4N f32
    float* bnstat = ws + (size_t)8 * N;               // 8
    float* bnsc   = bnstat + 8;                       // 8
    short* atomb  = (short*)(ws + (size_t)8 * N + 16);// N*32 bf16
    short* efb    = atomb + (size_t)N * 32;           // E*32 bf16
    short* outb   = efb + (size_t)E * 32;             // N*32 bf16

    // d_out: [out N*32 f32][eout E*32 f32]; eout region doubles as alpha scratch
    float* outp  = (float*)d_out;
    float* alpha = outp + (size_t)N * 32;             // 4E f32 (dead before eout write)
    float* eout  = outp + (size_t)N * 32;

    hipMemsetAsync(outp, 0, (size_t)N * 32 * sizeof(float), stream);
    hipMemsetAsync(ws, 0, ((size_t)8 * N + 16) * sizeof(float), stream);

    const int n4e = 4 * E;
    kprep<<<1024, 256, 0, stream>>>(atom, efea, atomb, efb, N * 8, E * 8);
    kBv  <<<2048, 256, 0, stream>>>(efb, eidx, atomb, Wg, attg, alpha, bnstat, E);
    k2_bn<<<1, 64, 0, stream>>>(bnstat, gam, bet, bnsc, E);
    k3_bnmax<<<(n4e + 255) / 256, 256, 0, stream>>>(alpha, eidx, (unsigned int*)mbuf, bnsc, E);
    k4_exps <<<(n4e + 255) / 256, 256, 0, stream>>>(alpha, eidx, mbuf, sbuf, E);
    kmsgv<<<2048, 256, 0, stream>>>(efb, eidx, atomb, Wg, alpha, sbuf, outp, E);
    kout <<<(N * 32 + 255) / 256, 256, 0, stream>>>(outp, bias, outb, N);
    kG2v <<<2048, 256, 0, stream>>>(efb, eidx, outb, W1g, W2g, b1g, b2g, eout, E);
}